// Round 18
// baseline (80.108 us; speedup 1.0000x reference)
//
#include <hip/hip_runtime.h>
#include <hip/hip_fp16.h>

// Problem constants
#define NB 4      // batch
#define NI 160    // input spatial size (all 3 dims)
#define NO 43     // output spatial size: ceil(160/4)+3
#define NC 3      // channels
#define KS 7      // gaussian kernel size per axis
#define KPAD 3    // (KS-1)/2
#define MT 16     // stored taps per banded row (true max = 14)
#define CH 8      // rows per chunk (fallback)
#define CH1 4     // rows per chunk in k_p1 (4 rows x 15 triples = 60 tasks)
#define P1B 64    // k_p1 block size = ONE WAVE
#define NP 22     // o2 pairs for p2 (21 full + 1 half)
#define NT 15     // o3 triples for p1 (14 full + 1 single)

#define ROWF (NI * NC)            // 480 floats per input row
#define PR 152                    // padded A-row: 15 groups x 10 halves + 2
#define PR4 (PR / 4)              // 38 h4-groups per row
#define LROW 484                  // LDS row stride (484 % 32 == 4)

#define A1H_BYTES ((size_t)NB * NI * NI * PR * 2)        // 31,129,600 (fp16)
#define A2H_BYTES ((size_t)NB * NI * NO * PR * 2)        // 8,366,080  (fp16)
#define P2P_THREADS ((size_t)NB * NI * NP * PR4)         // 535,040
#define P3_THREADS ((size_t)NB * NO * NO * PR4)          // 281,048

// ===========================================================================
// Compile-time tables. Taps outside a member's band (incl. j >= NI or
// o >= 43) are EXACTLY 0.0 — overrun reads multiply real-but-irrelevant
// data by zero; LDS slack beyond the last row is zeroed (no NaN*0).
// Padded layout: group g holds o3/o2 = 3g..3g+2 in 10 halves (9 vals + 0).
// ===========================================================================
struct __align__(16) Tables {
    float w1[NO][MT];       // banded 16-tap weights (p3 / fallback)
    float wp[NP][24][2];    // pair-union weights (p2 o2-pairs)
    float wt[NT][84];       // triple-union weights (p1): [28 taps][3 outs]
    int   o1hp[NP][24];     // p2 tap byte offsets, stride PR*2 = 304
    int   o0h[NO][MT];      // p3 tap byte offsets, stride NO*PR*2 = 13072
    int   j3[NO];           // pair-aligned window starts (mult of 4)
    int   j3t[NT];          // triple-aligned window starts (mult of 4)
    int   jlo[NO];          // band starts
};

constexpr double ctaylor(double r) {
    double s = 1.0, term = 1.0;
    for (int n = 1; n <= 13; ++n) { term *= r / (double)n; s += term; }
    return s;
}
constexpr double cexp_neg(double x) {
    double y = -x;
    int k = (int)(y * 16.0);
    double r = y - (double)k / 16.0;
    double e16 = ctaylor(1.0 / 16.0);
    double p = 1.0;
    for (int i = 0; i < k; ++i) p *= e16;
    return 1.0 / (p * ctaylor(r));
}
constexpr int cceil(double x)  { int c = (int)x; return ((double)c < x) ? c + 1 : c; }
constexpr int cfloor(double x) { int f = (int)x; return ((double)f > x) ? f - 1 : f; }
constexpr double cabsd(double x) { return x < 0 ? -x : x; }

constexpr double comp_w(int j, double sf, int ilo, int ihi, const double* g) {
    if (j >= NI || j < 0) return 0.0;
    double cw = 0.0;
    for (int t = 0; t < KS; ++t) {
        int i = j + KPAD - t;
        if (i >= ilo && i <= ihi) {
            double w = 1.0 - cabsd(sf - (double)i) * (43.0 / 160.0);
            if (w > 0.0) cw += g[t] * w;
        }
    }
    return cw;
}

struct Band { double sf; int ilo; int ihi; double wsum; };
constexpr Band bandof(int o) {
    const double inv_scale = 160.0 / 43.0;
    double sf = ((double)o + 0.5) * inv_scale - 0.5;
    int ilo = cceil(sf - inv_scale);  if (ilo < 0) ilo = 0;
    int ihi = cfloor(sf + inv_scale); if (ihi > NI - 1) ihi = NI - 1;
    double wsum = 0.0;
    for (int i = ilo; i <= ihi; ++i) {
        double w = 1.0 - cabsd(sf - (double)i) * (43.0 / 160.0);
        if (w > 0.0) wsum += w;
    }
    return {sf, ilo, ihi, wsum};
}

constexpr Tables make_tables() {
    Tables T{};
    double g[KS] = {};
    double gs = 0.0;
    const double sig = 0.44 * 4.0;
    for (int i = 0; i < KS; ++i) {
        double d = (double)i - 3.0;
        g[i] = cexp_neg(-(d * d) / (2.0 * sig * sig));
        gs += g[i];
    }
    for (int i = 0; i < KS; ++i) g[i] /= gs;

    for (int o = 0; o < NO; ++o) {
        Band B = bandof(o);
        int jlo = B.ilo - KPAD; if (jlo < 0) jlo = 0;
        T.j3[o] = jlo & ~3;
        T.jlo[o] = jlo;
        for (int k = 0; k < MT; ++k) {
            int j = jlo + k;
            T.w1[o][k] = (float)(comp_w(j, B.sf, B.ilo, B.ihi, g) / B.wsum);
            int jc = (j < NI) ? j : (NI - 1);
            T.o0h[o][k] = jc * (NO * PR * 2);       // p3 i1-stride 13072
        }
    }
    // p2 pair windows (24 taps from j3[2p])
    for (int p = 0; p < NP; ++p) {
        int oA = 2 * p, oB = 2 * p + 1;
        Band BA = bandof(oA);
        int jp = T.j3[oA];
        for (int k = 0; k < 24; ++k) {
            T.wp[p][k][0] = (float)(comp_w(jp + k, BA.sf, BA.ilo, BA.ihi, g) / BA.wsum);
            if (oB < NO) {
                Band BB = bandof(oB);
                T.wp[p][k][1] = (float)(comp_w(jp + k, BB.sf, BB.ilo, BB.ihi, g) / BB.wsum);
            } else {
                T.wp[p][k][1] = 0.0f;
            }
            int jc = (jp + k < NI) ? (jp + k) : (NI - 1);
            T.o1hp[p][k] = jc * (PR * 2);           // p2 i2-stride 304
        }
    }
    // p1 triple windows (28 taps from j3t[q]); w[k*3+m] = weight of o=3q+m
    for (int q = 0; q < NT; ++q) {
        int jq = T.jlo[3 * q] & ~3;
        T.j3t[q] = jq;
        for (int k = 0; k < 28; ++k) {
            for (int m = 0; m < 3; ++m) {
                int o = 3 * q + m;
                if (o < NO) {
                    Band B = bandof(o);
                    T.wt[q][k * 3 + m] =
                        (float)(comp_w(jq + k, B.sf, B.ilo, B.ihi, g) / B.wsum);
                } else {
                    T.wt[q][k * 3 + m] = 0.0f;
                }
            }
        }
    }
    return T;
}

__constant__ Tables dT = make_tables();

struct __align__(8) h4 { __half2 lo, hi; };
union h2u { __half2 h; unsigned int u; };

// ---------------------------------------------------------------------------
// P1 (r18): contract i3 -> o3-TRIPLE per thread. Single-wave block, 4 rows,
// 60/64 lanes; 21 ds_read_b128 per 9 outputs (-34% wave-LDS-ops vs pairs).
// Output: padded groups of 10 halves (9 vals + explicit 0) = 5 aligned
// dwords per thread — dword-granular everywhere (r11 lesson). Lanes 60-63
// zero the 2-half row tails.
// ---------------------------------------------------------------------------
__global__ __launch_bounds__(P1B) void k_p1(
        const float* __restrict__ img, __half* __restrict__ A1h) {
    __shared__ __align__(16) float rows[CH1 * LROW + 64];  // 2000 f
    int t = threadIdx.x;
    int blk = blockIdx.x;                  // (b*160+i1)*40 + chunk

    const int q = t % NT, row = t / NT;    // valid when t < 60
    const bool has = (t < NT * CH1);

    // triple weights -> regs (21 float4; overlaps staging)
    float4 w0,w1,w2,w3,w4,w5,w6,w7,w8,w9,w10,w11,w12,w13,w14,w15,w16,w17,w18,w19,w20;
    int jp = 0;
    if (has) {
        jp = dT.j3t[q];
        const float4* wf = (const float4*)dT.wt[q];
        w0=wf[0];  w1=wf[1];  w2=wf[2];  w3=wf[3];  w4=wf[4];  w5=wf[5];
        w6=wf[6];  w7=wf[7];  w8=wf[8];  w9=wf[9];  w10=wf[10]; w11=wf[11];
        w12=wf[12]; w13=wf[13]; w14=wf[14]; w15=wf[15]; w16=wf[16]; w17=wf[17];
        w18=wf[18]; w19=wf[19]; w20=wf[20];
    }

    // stage 4 rows (480 float4, coalesced)
    const float4* src = (const float4*)(img + (size_t)blk * (CH1 * ROWF));
    for (int g = t; g < CH1 * ROWF / 4; g += P1B) {
        int r = g / 120, m = g % 120;
        *(float4*)(rows + r * LROW + 4 * m) = src[g];
    }
    if (t < CH1 * 4) rows[(t >> 2) * LROW + ROWF + (t & 3)] = 0.f;  // row pads
    rows[CH1 * LROW + t] = 0.f;                                     // 64 slack
    __syncthreads();   // single wave -> ~waitcnt

    if (has) {
        const float4* dp = (const float4*)(rows + row * LROW + 3 * jp);
        float a00=0.f,a01=0.f,a02=0.f, a10=0.f,a11=0.f,a12=0.f,
              a20=0.f,a21=0.f,a22=0.f;
#define TAP9(WM0,WM1,WM2, VC0,VC1,VC2)                                         \
        a00 += (WM0)*(VC0); a01 += (WM0)*(VC1); a02 += (WM0)*(VC2);            \
        a10 += (WM1)*(VC0); a11 += (WM1)*(VC1); a12 += (WM1)*(VC2);            \
        a20 += (WM2)*(VC0); a21 += (WM2)*(VC1); a22 += (WM2)*(VC2);
#define STEP(M, WA, WB, WC) {                                                  \
        float4 v0 = dp[3*(M)], v1 = dp[3*(M)+1], v2 = dp[3*(M)+2];             \
        TAP9(WA.x, WA.y, WA.z, v0.x, v0.y, v0.z)                               \
        TAP9(WA.w, WB.x, WB.y, v0.w, v1.x, v1.y)                               \
        TAP9(WB.z, WB.w, WC.x, v1.z, v1.w, v2.x)                               \
        TAP9(WC.y, WC.z, WC.w, v2.y, v2.z, v2.w) }
        STEP(0, w0,  w1,  w2)   STEP(1, w3,  w4,  w5)
        STEP(2, w6,  w7,  w8)   STEP(3, w9,  w10, w11)
        STEP(4, w12, w13, w14)  STEP(5, w15, w16, w17)
        STEP(6, w18, w19, w20)
#undef STEP
#undef TAP9
        h2u c0, c1, c2, c3, c4;
        c0.h = __floats2half2_rn(a00, a01);
        c1.h = __floats2half2_rn(a02, a10);
        c2.h = __floats2half2_rn(a11, a12);
        c3.h = __floats2half2_rn(a20, a21);
        c4.h = __floats2half2_rn(a22, 0.f);
        unsigned int* dstu = (unsigned int*)A1h;
        size_t baseu = ((size_t)blk * CH1 + row) * (PR / 2) + 5 * q;
        dstu[baseu]     = c0.u; dstu[baseu + 1] = c1.u; dstu[baseu + 2] = c2.u;
        dstu[baseu + 3] = c3.u; dstu[baseu + 4] = c4.u;
    } else {
        // lanes 60..63: zero halves [150,152) of their row (1 dword)
        int r = t - NT * CH1;
        ((unsigned int*)A1h)[((size_t)blk * CH1 + r) * (PR / 2) + 75] = 0u;
    }
}

// Bijective XCD-chunked block swizzle (m204 form).
__device__ __forceinline__ int xcd_swz(int wg, int nwg) {
    int q = nwg >> 3, r = nwg & 7;
    int x = wg & 7, i = wg >> 3;
    return (x < r ? x * (q + 1) : r * (q + 1) + (x - r) * q) + i;
}

// ---------------------------------------------------------------------------
// P2: contract i2 -> o2-PAIR per thread (24-tap union window) over the
// padded 152-col rows. fp16 in/out, 8B h4 loads/stores (dword-granular).
// Pads are exact zeros and flow through as 0*w.
// ---------------------------------------------------------------------------
__global__ __launch_bounds__(256) void k_p2(
        const __half* __restrict__ A1h, __half* __restrict__ A2h) {
    int blk = xcd_swz(blockIdx.x, gridDim.x);
    size_t idx = (size_t)blk * 256 + threadIdx.x;
    if (idx >= P2P_THREADS) return;
    int ii = (int)idx;
    int col4 = ii % PR4;
    int p    = (ii / PR4) % NP;
    int slab = ii / (PR4 * NP);             // b*160 + i1
    const char* base = (const char*)A1h + ((size_t)slab * NI * PR + col4 * 4) * 2;
    const float4* wpp = (const float4*)dT.wp[p];
    const int4*   ot  = (const int4*)dT.o1hp[p];
    float4 wq0 = wpp[0], wq1 = wpp[1], wq2 = wpp[2],  wq3 = wpp[3];
    float4 wq4 = wpp[4], wq5 = wpp[5], wq6 = wpp[6],  wq7 = wpp[7];
    float4 wq8 = wpp[8], wq9 = wpp[9], wq10 = wpp[10], wq11 = wpp[11];
    int4 t0 = ot[0], t1 = ot[1], t2 = ot[2], t3 = ot[3], t4 = ot[4], t5 = ot[5];
    float4 a = {0.f,0.f,0.f,0.f}, b = a;
#define TP(J, WA, WB) { h4 v = *(const h4*)(base + (unsigned)(J));             \
        float2 f0 = __half22float2(v.lo), f1 = __half22float2(v.hi);           \
        a.x += (WA) * f0.x; a.y += (WA) * f0.y;                                \
        a.z += (WA) * f1.x; a.w += (WA) * f1.y;                                \
        b.x += (WB) * f0.x; b.y += (WB) * f0.y;                                \
        b.z += (WB) * f1.x; b.w += (WB) * f1.y; }
    TP(t0.x, wq0.x, wq0.y)  TP(t0.y, wq0.z, wq0.w)
    TP(t0.z, wq1.x, wq1.y)  TP(t0.w, wq1.z, wq1.w)
    TP(t1.x, wq2.x, wq2.y)  TP(t1.y, wq2.z, wq2.w)
    TP(t1.z, wq3.x, wq3.y)  TP(t1.w, wq3.z, wq3.w)
    TP(t2.x, wq4.x, wq4.y)  TP(t2.y, wq4.z, wq4.w)
    TP(t2.z, wq5.x, wq5.y)  TP(t2.w, wq5.z, wq5.w)
    TP(t3.x, wq6.x, wq6.y)  TP(t3.y, wq6.z, wq6.w)
    TP(t3.z, wq7.x, wq7.y)  TP(t3.w, wq7.z, wq7.w)
    TP(t4.x, wq8.x, wq8.y)  TP(t4.y, wq8.z, wq8.w)
    TP(t4.z, wq9.x, wq9.y)  TP(t4.w, wq9.z, wq9.w)
    TP(t5.x, wq10.x, wq10.y) TP(t5.y, wq10.z, wq10.w)
    TP(t5.z, wq11.x, wq11.y) TP(t5.w, wq11.z, wq11.w)
#undef TP
    h4* A2h4 = (h4*)A2h;
    size_t rbase = ((size_t)slab * NO + 2 * p) * PR4 + col4;
    h4 ra; ra.lo = __floats2half2_rn(a.x, a.y); ra.hi = __floats2half2_rn(a.z, a.w);
    A2h4[rbase] = ra;
    if (2 * p + 1 < NO) {
        h4 rb; rb.lo = __floats2half2_rn(b.x, b.y); rb.hi = __floats2half2_rn(b.z, b.w);
        A2h4[rbase + PR4] = rb;
    }
}

// ---------------------------------------------------------------------------
// P3: contract i1 -> o1 from fp16 A2h (padded cols). Scalar stores map
// padded col -> compact (o3,c): group g, slot r<9 -> oc = 9g + r; skip
// r==9 and oc >= 129 (q=14's unused slots, zeros).
// ---------------------------------------------------------------------------
__global__ __launch_bounds__(256) void k_p3(
        const __half* __restrict__ A2h, float* __restrict__ out) {
    int blk = xcd_swz(blockIdx.x, gridDim.x);
    size_t idx = (size_t)blk * 256 + threadIdx.x;
    if (idx >= P3_THREADS) return;
    int ii = (int)idx;
    int col4 = ii % PR4;
    int o2   = (ii / PR4) % NO;
    int o1   = (ii / (PR4 * NO)) % NO;
    int b    = ii / (PR4 * NO * NO);
    const char* base = (const char*)A2h +
        (((size_t)b * NI * NO + o2) * PR + col4 * 4) * 2;
    const float4* wv = (const float4*)dT.w1[o1];
    const int4*   ov = (const int4*)dT.o0h[o1];
    float4 w0 = wv[0], w1v = wv[1], w2 = wv[2], w3 = wv[3];
    int4   j0 = ov[0], j1 = ov[1], j2 = ov[2], j3 = ov[3];
    float4 a = {0.f, 0.f, 0.f, 0.f};
#define TAP4H(J, W) { h4 v = *(const h4*)(base + (unsigned)(J));               \
                      float2 f0 = __half22float2(v.lo);                        \
                      float2 f1 = __half22float2(v.hi);                        \
                      a.x += (W) * f0.x; a.y += (W) * f0.y;                    \
                      a.z += (W) * f1.x; a.w += (W) * f1.y; }
    TAP4H(j0.x, w0.x) TAP4H(j0.y, w0.y) TAP4H(j0.z, w0.z) TAP4H(j0.w, w0.w)
    TAP4H(j1.x, w1v.x) TAP4H(j1.y, w1v.y) TAP4H(j1.z, w1v.z) TAP4H(j1.w, w1v.w)
    TAP4H(j2.x, w2.x) TAP4H(j2.y, w2.y) TAP4H(j2.z, w2.z) TAP4H(j2.w, w2.w)
    TAP4H(j3.x, w3.x) TAP4H(j3.y, w3.y) TAP4H(j3.z, w3.z) TAP4H(j3.w, w3.w)
#undef TAP4H
    int tile = (b * NO + o1) * NO + o2;
    float* ob = out + (size_t)tile * (NO * NC);
    float av[4] = {a.x, a.y, a.z, a.w};
    #pragma unroll
    for (int e = 0; e < 4; ++e) {
        int pc = col4 * 4 + e;
        int g = pc / 10, r = pc % 10;
        if (r < 9) {
            int oc = g * 9 + r;
            if (oc < NO * NC) ob[oc] = av[e];
        }
    }
}

// ---------------------------------------------------------------------------
// FALLBACK (r1-structure, known-correct), fp32, setup-free.
// ---------------------------------------------------------------------------
__global__ __launch_bounds__(256) void k_passA(
        const float* __restrict__ img, float* __restrict__ S) {
    __shared__ float rows[CH * NI * NC];
    __shared__ float T[CH * NO * NC];
    __shared__ float acc[NO * NO * NC];
    __shared__ float w2[NO * MT];
    __shared__ int   s2[NO];
    int t = threadIdx.x;
    int blk = blockIdx.x;
    const float* src = img + (size_t)blk * (NI * NI * NC);
    for (int k = t; k < NO * MT; k += 256) w2[k] = ((const float*)dT.w1)[k];
    for (int k = t; k < NO; k += 256) s2[k] = dT.jlo[k];
    for (int k = t; k < NO * NO * NC; k += 256) acc[k] = 0.f;
    __syncthreads();
    for (int chunk = 0; chunk < NI / CH; ++chunk) {
        const float4* csrc = (const float4*)(src + (size_t)chunk * CH * NI * NC);
        for (int k = t; k < CH * NI * NC / 4; k += 256)
            ((float4*)rows)[k] = csrc[k];
        __syncthreads();
        for (int task = t; task < CH * NO; task += 256) {
            int ch = task / NO, o3 = task % NO;
            int st = s2[o3];
            const float* rp = rows + ch * NI * NC;
            float a0 = 0.f, a1 = 0.f, a2 = 0.f;
            #pragma unroll
            for (int k = 0; k < MT; ++k) {
                int j = st + k; j = (j < NI) ? j : (NI - 1);
                float w = w2[o3 * MT + k];
                a0 += w * rp[j * 3 + 0];
                a1 += w * rp[j * 3 + 1];
                a2 += w * rp[j * 3 + 2];
            }
            T[task * NC + 0] = a0;
            T[task * NC + 1] = a1;
            T[task * NC + 2] = a2;
        }
        __syncthreads();
        int i2base = chunk * CH;
        for (int task = t; task < NO * NO; task += 256) {
            int o2 = task / NO, o3 = task % NO;
            int st = s2[o2];
            int k0 = i2base - st;        k0 = (k0 > 0) ? k0 : 0;
            int k1 = i2base + CH - st;   k1 = (k1 < MT) ? k1 : MT;
            if (k1 > k0) {
                float a0 = 0.f, a1 = 0.f, a2 = 0.f;
                for (int k = k0; k < k1; ++k) {
                    float w = w2[o2 * MT + k];
                    int ch = st + k - i2base;
                    a0 += w * T[(ch * NO + o3) * NC + 0];
                    a1 += w * T[(ch * NO + o3) * NC + 1];
                    a2 += w * T[(ch * NO + o3) * NC + 2];
                }
                acc[task * NC + 0] += a0;
                acc[task * NC + 1] += a1;
                acc[task * NC + 2] += a2;
            }
        }
        __syncthreads();
    }
    float* Sp = S + (size_t)blk * (NO * NO * NC);
    for (int k = t; k < NO * NO * NC; k += 256) Sp[k] = acc[k];
}

__global__ __launch_bounds__(256) void k_passB(
        const float* __restrict__ S, float* __restrict__ out) {
    int blk = blockIdx.x;
    int b = blk / NO, o1 = blk % NO;
    __shared__ float w1s[MT];
    __shared__ int s1v;
    if (threadIdx.x < MT) w1s[threadIdx.x] = dT.w1[o1][threadIdx.x];
    if (threadIdx.x == 0) s1v = dT.jlo[o1];
    __syncthreads();
    const float* Sb = S + (size_t)b * NI * (NO * NO * NC);
    float* ob = out + (size_t)blk * (NO * NO * NC);
    int st = s1v;
    for (int e = threadIdx.x; e < NO * NO * NC; e += 256) {
        float a = 0.f;
        #pragma unroll
        for (int k = 0; k < MT; ++k) {
            int i1 = st + k; i1 = (i1 < NI) ? i1 : (NI - 1);
            a += w1s[k] * Sb[(size_t)i1 * (NO * NO * NC) + e];
        }
        ob[e] = a;
    }
}

// ---------------------------------------------------------------------------
extern "C" void kernel_launch(void* const* d_in, const int* in_sizes, int n_in,
                              void* d_out, int out_size, void* d_ws, size_t ws_size,
                              hipStream_t stream) {
    (void)in_sizes; (void)n_in; (void)out_size;
    const float* img = (const float*)d_in[0];
    float* out = (float*)d_out;
    char* ws = (char*)d_ws;

    if (ws_size >= A1H_BYTES + A2H_BYTES) {
        __half* A1h = (__half*)ws;
        __half* A2h = (__half*)(ws + A1H_BYTES);
        k_p1<<<NB * NI * (NI / CH1), P1B, 0, stream>>>(img, A1h);
        int p2b = (int)((P2P_THREADS + 255) / 256);
        k_p2<<<p2b, 256, 0, stream>>>(A1h, A2h);
        int p3b = (int)((P3_THREADS + 255) / 256);
        k_p3<<<p3b, 256, 0, stream>>>(A2h, out);
    } else {
        float* S = (float*)ws;                       // 14.2 MB
        k_passA<<<NB * NI, 256, 0, stream>>>(img, S);
        k_passB<<<NB * NO, 256, 0, stream>>>(S, out);
    }
}

// Round 19
// 65.105 us; speedup vs baseline: 1.2305x; 1.2305x over previous
//
#include <hip/hip_runtime.h>
#include <hip/hip_fp16.h>

// Problem constants
#define NB 4      // batch
#define NI 160    // input spatial size (all 3 dims)
#define NO 43     // output spatial size: ceil(160/4)+3
#define NC 3      // channels
#define KS 7      // gaussian kernel size per axis
#define KPAD 3    // (KS-1)/2
#define MT 16     // stored taps per banded row (true max = 14)
#define CH 8      // rows per chunk (fallback)
#define CH1 2     // rows per chunk in k_p1 (2 rows -> single-wave block)
#define P1B 64    // k_p1 block size = ONE WAVE (barrier ~free)
#define NP 22     // pairs (21 full + 1 half) — shared by p1 (o3) and p2 (o2)

#define ROWF (NI * NC)            // 480 floats per input row
#define PROW 132                  // padded (o3,c) row: 129 -> 132 elems
#define PROW4 (PROW / 4)          // 33 groups of 4
#define LROW 484                  // LDS row stride (484 % 32 == 4)
#define SLICE (NO * NO * NC)

#define A1H_BYTES ((size_t)NB * NI * NI * PROW * 2)      // 27,033,600 (fp16)
#define A2H_BYTES ((size_t)NB * NI * NO * PROW * 2)      // 7,265,280  (fp16)
#define P2P_THREADS ((size_t)NB * NI * NP * PROW4)       // 464,640
#define P3_THREADS ((size_t)NB * NO * NO * PROW4)        // 244,068

// ===========================================================================
// Compile-time weight tables (wp pair-union validated r14/r15/r17).
// Taps outside a member's band (incl. j >= NI) are EXACTLY 0.0 — this makes
// the window overrun past row end harmless (garbage x 0 = 0).
// ===========================================================================
struct __align__(16) Tables {
    float w1[NO][MT];       // banded 16-tap weights (p3 / fallback)
    float wp[NP][24][2];    // pair-union weights (p1 o3-pairs, p2 o2-pairs)
    int   o1hp[NP][24];     // byte offsets for p2 pair taps, stride PROW*2=264
    int   o0h[NO][MT];      // byte offsets for p3 taps, stride NO*PROW*2=11352
    int   j3[NO];           // aligned window starts (multiples of 4)
    int   jlo[NO];          // band starts
};

constexpr double ctaylor(double r) {            // exp(r), r in [0, 1/16]
    double s = 1.0, term = 1.0;
    for (int n = 1; n <= 13; ++n) { term *= r / (double)n; s += term; }
    return s;
}
constexpr double cexp_neg(double x) {           // exp(x), x <= 0, |x| < 40
    double y = -x;
    int k = (int)(y * 16.0);
    double r = y - (double)k / 16.0;
    double e16 = ctaylor(1.0 / 16.0);
    double p = 1.0;
    for (int i = 0; i < k; ++i) p *= e16;
    return 1.0 / (p * ctaylor(r));
}
constexpr int cceil(double x)  { int c = (int)x; return ((double)c < x) ? c + 1 : c; }
constexpr int cfloor(double x) { int f = (int)x; return ((double)f > x) ? f - 1 : f; }
constexpr double cabsd(double x) { return x < 0 ? -x : x; }

constexpr double comp_w(int j, double sf, int ilo, int ihi, const double* g) {
    if (j >= NI || j < 0) return 0.0;           // taps at j>=NI are exactly 0
    double cw = 0.0;
    for (int t = 0; t < KS; ++t) {
        int i = j + KPAD - t;
        if (i >= ilo && i <= ihi) {
            double w = 1.0 - cabsd(sf - (double)i) * (43.0 / 160.0);
            if (w > 0.0) cw += g[t] * w;
        }
    }
    return cw;
}

struct Band { double sf; int ilo; int ihi; double wsum; };
constexpr Band bandof(int o) {
    const double inv_scale = 160.0 / 43.0;
    double sf = ((double)o + 0.5) * inv_scale - 0.5;
    int ilo = cceil(sf - inv_scale);  if (ilo < 0) ilo = 0;
    int ihi = cfloor(sf + inv_scale); if (ihi > NI - 1) ihi = NI - 1;
    double wsum = 0.0;
    for (int i = ilo; i <= ihi; ++i) {
        double w = 1.0 - cabsd(sf - (double)i) * (43.0 / 160.0);
        if (w > 0.0) wsum += w;
    }
    return {sf, ilo, ihi, wsum};
}

constexpr Tables make_tables() {
    Tables T{};
    double g[KS] = {};
    double gs = 0.0;
    const double sig = 0.44 * 4.0;
    for (int i = 0; i < KS; ++i) {
        double d = (double)i - 3.0;
        g[i] = cexp_neg(-(d * d) / (2.0 * sig * sig));
        gs += g[i];
    }
    for (int i = 0; i < KS; ++i) g[i] /= gs;

    for (int o = 0; o < NO; ++o) {
        Band B = bandof(o);
        int jlo = B.ilo - KPAD; if (jlo < 0) jlo = 0;
        T.j3[o] = jlo & ~3;
        T.jlo[o] = jlo;
        for (int k = 0; k < MT; ++k) {
            int j = jlo + k;
            T.w1[o][k] = (float)(comp_w(j, B.sf, B.ilo, B.ihi, g) / B.wsum);
            int jc = (j < NI) ? j : (NI - 1);       // pad taps have w=0
            T.o0h[o][k] = jc * (NO * PROW * 2);     // fp16 A2 i1-stride
        }
    }
    // pair-union windows (frame = 24 taps from j3[2p])
    for (int p = 0; p < NP; ++p) {
        int oA = 2 * p, oB = 2 * p + 1;
        Band BA = bandof(oA);
        int jp = T.j3[oA];
        for (int k = 0; k < 24; ++k) {
            T.wp[p][k][0] = (float)(comp_w(jp + k, BA.sf, BA.ilo, BA.ihi, g) / BA.wsum);
            if (oB < NO) {
                Band BB = bandof(oB);
                T.wp[p][k][1] = (float)(comp_w(jp + k, BB.sf, BB.ilo, BB.ihi, g) / BB.wsum);
            } else {
                T.wp[p][k][1] = 0.0f;               // unpaired tail
            }
            int jc = (jp + k < NI) ? (jp + k) : (NI - 1);
            T.o1hp[p][k] = jc * (PROW * 2);         // fp16 A1 i2-stride
        }
    }
    return T;
}

__constant__ Tables dT = make_tables();

struct __align__(8) h4 { __half2 lo, hi; };
union h2u { __half2 h; unsigned int u; };

// ---------------------------------------------------------------------------
// P1 (r17, best measured): LDS-staged, SINGLE-WAVE blocks: 2 rows/block,
// 64 threads. The stage->compute barrier is intra-wave (compiles to a
// waitcnt); 51200 tiny blocks interleave staging stalls across the CU.
// Compute = r14's verified STEP math from LDS; dword-granular stores.
// ---------------------------------------------------------------------------
__global__ __launch_bounds__(P1B) void k_p1(
        const float* __restrict__ img, __half* __restrict__ A1h) {
    __shared__ __align__(16) float rows[CH1 * LROW + 64];  // 1032 f ~ 4.1 KB
    int t = threadIdx.x;
    int blk = blockIdx.x;                  // (b*160+i1)*80 + chunk

    const int p = t % NP, row = t / NP;    // valid when t < 44
    const bool has = (t < NP * CH1);

    // weight preload (constant mem; overlaps staging)
    float4 wq0, wq1, wq2, wq3, wq4, wq5, wq6, wq7, wq8, wq9, wq10, wq11;
    int jp = 0;
    if (has) {
        jp = dT.j3[2 * p];
        const float4* wpp = (const float4*)dT.wp[p];
        wq0 = wpp[0];  wq1 = wpp[1];  wq2 = wpp[2];  wq3 = wpp[3];
        wq4 = wpp[4];  wq5 = wpp[5];  wq6 = wpp[6];  wq7 = wpp[7];
        wq8 = wpp[8];  wq9 = wpp[9];  wq10 = wpp[10]; wq11 = wpp[11];
    }

    // stage 2 rows (240 float4, coalesced)
    const float4* src = (const float4*)(img + (size_t)blk * (CH1 * ROWF));
    for (int g = t; g < CH1 * ROWF / 4; g += P1B) {
        int r = g / 120, m = g % 120;
        *(float4*)(rows + r * LROW + 4 * m) = src[g];
    }
    if (t < CH1 * 4) rows[(t >> 2) * LROW + ROWF + (t & 3)] = 0.f;  // row pads
    rows[CH1 * LROW + t] = 0.f;                                     // 64 slack
    __syncthreads();   // single wave -> effectively just a waitcnt

    if (has) {
        const float4* dp = (const float4*)(rows + row * LROW + 3 * jp);
        float a0 = 0.f, a1 = 0.f, a2 = 0.f;    // o3 = 2p
        float b0 = 0.f, b1 = 0.f, b2 = 0.f;    // o3 = 2p+1
#define STEP(M, WQA, WQB) {                                                    \
            float4 v0 = dp[3*(M)], v1 = dp[3*(M)+1], v2 = dp[3*(M)+2];         \
            a0 += WQA.x * v0.x; a1 += WQA.x * v0.y; a2 += WQA.x * v0.z;        \
            b0 += WQA.y * v0.x; b1 += WQA.y * v0.y; b2 += WQA.y * v0.z;        \
            a0 += WQA.z * v0.w; a1 += WQA.z * v1.x; a2 += WQA.z * v1.y;        \
            b0 += WQA.w * v0.w; b1 += WQA.w * v1.x; b2 += WQA.w * v1.y;        \
            a0 += WQB.x * v1.z; a1 += WQB.x * v1.w; a2 += WQB.x * v2.x;        \
            b0 += WQB.y * v1.z; b1 += WQB.y * v1.w; b2 += WQB.y * v2.x;        \
            a0 += WQB.z * v2.y; a1 += WQB.z * v2.z; a2 += WQB.z * v2.w;        \
            b0 += WQB.w * v2.y; b1 += WQB.w * v2.z; b2 += WQB.w * v2.w;        \
        }
        STEP(0, wq0, wq1)  STEP(1, wq2, wq3)  STEP(2, wq4, wq5)
        STEP(3, wq6, wq7)  STEP(4, wq8, wq9)  STEP(5, wq10, wq11)
#undef STEP
        h2u c0, c1, c2;
        c0.h = __floats2half2_rn(a0, a1);
        c1.h = __floats2half2_rn(a2, b0);
        c2.h = __floats2half2_rn(b1, b2);
        unsigned int* dstu = (unsigned int*)A1h;
        size_t baseu = ((size_t)blk * CH1 + row) * (PROW / 2) + 3 * p;
        dstu[baseu] = c0.u; dstu[baseu + 1] = c1.u; dstu[baseu + 2] = c2.u;
    }
}

// Bijective XCD-chunked block swizzle (m204 form).
__device__ __forceinline__ int xcd_swz(int wg, int nwg) {
    int q = nwg >> 3, r = nwg & 7;
    int x = wg & 7, i = wg >> 3;
    return (x < r ? x * (q + 1) : r * (q + 1) + (x - r) * q) + i;
}

// ---------------------------------------------------------------------------
// P2: contract i2 -> o2-PAIR per thread (union window, 24 taps), output
// fp16 A2h[b][i1][o2][132]. 8B h4 stores. (r15-proven)
// ---------------------------------------------------------------------------
__global__ __launch_bounds__(256) void k_p2(
        const __half* __restrict__ A1h, __half* __restrict__ A2h) {
    int blk = xcd_swz(blockIdx.x, gridDim.x);
    size_t idx = (size_t)blk * 256 + threadIdx.x;
    if (idx >= P2P_THREADS) return;
    int ii = (int)idx;
    int col4 = ii % PROW4;
    int p    = (ii / PROW4) % NP;
    int slab = ii / (PROW4 * NP);           // b*160 + i1
    const char* base = (const char*)A1h + ((size_t)slab * NI * PROW + col4 * 4) * 2;
    const float4* wpp = (const float4*)dT.wp[p];
    const int4*   ot  = (const int4*)dT.o1hp[p];
    float4 wq0 = wpp[0], wq1 = wpp[1], wq2 = wpp[2],  wq3 = wpp[3];
    float4 wq4 = wpp[4], wq5 = wpp[5], wq6 = wpp[6],  wq7 = wpp[7];
    float4 wq8 = wpp[8], wq9 = wpp[9], wq10 = wpp[10], wq11 = wpp[11];
    int4 t0 = ot[0], t1 = ot[1], t2 = ot[2], t3 = ot[3], t4 = ot[4], t5 = ot[5];
    float4 a = {0.f,0.f,0.f,0.f}, b = a;
#define TP(J, WA, WB) { h4 v = *(const h4*)(base + (unsigned)(J));             \
        float2 f0 = __half22float2(v.lo), f1 = __half22float2(v.hi);           \
        a.x += (WA) * f0.x; a.y += (WA) * f0.y;                                \
        a.z += (WA) * f1.x; a.w += (WA) * f1.y;                                \
        b.x += (WB) * f0.x; b.y += (WB) * f0.y;                                \
        b.z += (WB) * f1.x; b.w += (WB) * f1.y; }
    TP(t0.x, wq0.x, wq0.y)  TP(t0.y, wq0.z, wq0.w)
    TP(t0.z, wq1.x, wq1.y)  TP(t0.w, wq1.z, wq1.w)
    TP(t1.x, wq2.x, wq2.y)  TP(t1.y, wq2.z, wq2.w)
    TP(t1.z, wq3.x, wq3.y)  TP(t1.w, wq3.z, wq3.w)
    TP(t2.x, wq4.x, wq4.y)  TP(t2.y, wq4.z, wq4.w)
    TP(t2.z, wq5.x, wq5.y)  TP(t2.w, wq5.z, wq5.w)
    TP(t3.x, wq6.x, wq6.y)  TP(t3.y, wq6.z, wq6.w)
    TP(t3.z, wq7.x, wq7.y)  TP(t3.w, wq7.z, wq7.w)
    TP(t4.x, wq8.x, wq8.y)  TP(t4.y, wq8.z, wq8.w)
    TP(t4.z, wq9.x, wq9.y)  TP(t4.w, wq9.z, wq9.w)
    TP(t5.x, wq10.x, wq10.y) TP(t5.y, wq10.z, wq10.w)
    TP(t5.z, wq11.x, wq11.y) TP(t5.w, wq11.z, wq11.w)
#undef TP
    h4* A2h4 = (h4*)A2h;
    size_t rbase = ((size_t)slab * NO + 2 * p) * PROW4 + col4;
    h4 ra; ra.lo = __floats2half2_rn(a.x, a.y); ra.hi = __floats2half2_rn(a.z, a.w);
    A2h4[rbase] = ra;
    if (2 * p + 1 < NO) {
        h4 rb; rb.lo = __floats2half2_rn(b.x, b.y); rb.hi = __floats2half2_rn(b.z, b.w);
        A2h4[rbase + PROW4] = rb;
    }
}

// ---------------------------------------------------------------------------
// P3: contract i1 -> o1 from fp16 A2h. out[b][o1][o2][o3][c] fp32
// (unpadded 129 cols, masked). (r15-proven)
// ---------------------------------------------------------------------------
__global__ __launch_bounds__(256) void k_p3(
        const __half* __restrict__ A2h, float* __restrict__ out) {
    int blk = xcd_swz(blockIdx.x, gridDim.x);
    size_t idx = (size_t)blk * 256 + threadIdx.x;
    if (idx >= P3_THREADS) return;
    int ii = (int)idx;
    int col4 = ii % PROW4;
    int o2   = (ii / PROW4) % NO;
    int o1   = (ii / (PROW4 * NO)) % NO;
    int b    = ii / (PROW4 * NO * NO);
    const char* base = (const char*)A2h +
        (((size_t)b * NI * NO + o2) * PROW + col4 * 4) * 2;
    const float4* wv = (const float4*)dT.w1[o1];
    const int4*   ov = (const int4*)dT.o0h[o1];
    float4 w0 = wv[0], w1v = wv[1], w2 = wv[2], w3 = wv[3];
    int4   j0 = ov[0], j1 = ov[1], j2 = ov[2], j3 = ov[3];
    float4 a = {0.f, 0.f, 0.f, 0.f};
#define TAP4H(J, W) { h4 v = *(const h4*)(base + (unsigned)(J));               \
                      float2 f0 = __half22float2(v.lo);                        \
                      float2 f1 = __half22float2(v.hi);                        \
                      a.x += (W) * f0.x; a.y += (W) * f0.y;                    \
                      a.z += (W) * f1.x; a.w += (W) * f1.y; }
    TAP4H(j0.x, w0.x) TAP4H(j0.y, w0.y) TAP4H(j0.z, w0.z) TAP4H(j0.w, w0.w)
    TAP4H(j1.x, w1v.x) TAP4H(j1.y, w1v.y) TAP4H(j1.z, w1v.z) TAP4H(j1.w, w1v.w)
    TAP4H(j2.x, w2.x) TAP4H(j2.y, w2.y) TAP4H(j2.z, w2.z) TAP4H(j2.w, w2.w)
    TAP4H(j3.x, w3.x) TAP4H(j3.y, w3.y) TAP4H(j3.z, w3.z) TAP4H(j3.w, w3.w)
#undef TAP4H
    int tile = (b * NO + o1) * NO + o2;
    float* ob = out + (size_t)tile * (NO * NC) + col4 * 4;
    int col = col4 * 4;
    float av[4] = {a.x, a.y, a.z, a.w};
    #pragma unroll
    for (int e = 0; e < 4; ++e)
        if (col + e < NO * NC) ob[e] = av[e];
}

// ---------------------------------------------------------------------------
// FALLBACK (r1-structure, known-correct), fp32, setup-free.
// ---------------------------------------------------------------------------
__global__ __launch_bounds__(256) void k_passA(
        const float* __restrict__ img, float* __restrict__ S) {
    __shared__ float rows[CH * NI * NC];
    __shared__ float T[CH * NO * NC];
    __shared__ float acc[NO * NO * NC];
    __shared__ float w2[NO * MT];
    __shared__ int   s2[NO];
    int t = threadIdx.x;
    int blk = blockIdx.x;
    const float* src = img + (size_t)blk * (NI * NI * NC);
    for (int k = t; k < NO * MT; k += 256) w2[k] = ((const float*)dT.w1)[k];
    for (int k = t; k < NO; k += 256) s2[k] = dT.jlo[k];
    for (int k = t; k < NO * NO * NC; k += 256) acc[k] = 0.f;
    __syncthreads();
    for (int chunk = 0; chunk < NI / CH; ++chunk) {
        const float4* csrc = (const float4*)(src + (size_t)chunk * CH * NI * NC);
        for (int k = t; k < CH * NI * NC / 4; k += 256)
            ((float4*)rows)[k] = csrc[k];
        __syncthreads();
        for (int task = t; task < CH * NO; task += 256) {
            int ch = task / NO, o3 = task % NO;
            int st = s2[o3];
            const float* rp = rows + ch * NI * NC;
            float a0 = 0.f, a1 = 0.f, a2 = 0.f;
            #pragma unroll
            for (int k = 0; k < MT; ++k) {
                int j = st + k; j = (j < NI) ? j : (NI - 1);
                float w = w2[o3 * MT + k];
                a0 += w * rp[j * 3 + 0];
                a1 += w * rp[j * 3 + 1];
                a2 += w * rp[j * 3 + 2];
            }
            T[task * NC + 0] = a0;
            T[task * NC + 1] = a1;
            T[task * NC + 2] = a2;
        }
        __syncthreads();
        int i2base = chunk * CH;
        for (int task = t; task < NO * NO; task += 256) {
            int o2 = task / NO, o3 = task % NO;
            int st = s2[o2];
            int k0 = i2base - st;        k0 = (k0 > 0) ? k0 : 0;
            int k1 = i2base + CH - st;   k1 = (k1 < MT) ? k1 : MT;
            if (k1 > k0) {
                float a0 = 0.f, a1 = 0.f, a2 = 0.f;
                for (int k = k0; k < k1; ++k) {
                    float w = w2[o2 * MT + k];
                    int ch = st + k - i2base;
                    a0 += w * T[(ch * NO + o3) * NC + 0];
                    a1 += w * T[(ch * NO + o3) * NC + 1];
                    a2 += w * T[(ch * NO + o3) * NC + 2];
                }
                acc[task * NC + 0] += a0;
                acc[task * NC + 1] += a1;
                acc[task * NC + 2] += a2;
            }
        }
        __syncthreads();
    }
    float* Sp = S + (size_t)blk * (NO * NO * NC);
    for (int k = t; k < NO * NO * NC; k += 256) Sp[k] = acc[k];
}

__global__ __launch_bounds__(256) void k_passB(
        const float* __restrict__ S, float* __restrict__ out) {
    int blk = blockIdx.x;
    int b = blk / NO, o1 = blk % NO;
    __shared__ float w1s[MT];
    __shared__ int s1v;
    if (threadIdx.x < MT) w1s[threadIdx.x] = dT.w1[o1][threadIdx.x];
    if (threadIdx.x == 0) s1v = dT.jlo[o1];
    __syncthreads();
    const float* Sb = S + (size_t)b * NI * (NO * NO * NC);
    float* ob = out + (size_t)blk * (NO * NO * NC);
    int st = s1v;
    for (int e = threadIdx.x; e < NO * NO * NC; e += 256) {
        float a = 0.f;
        #pragma unroll
        for (int k = 0; k < MT; ++k) {
            int i1 = st + k; i1 = (i1 < NI) ? i1 : (NI - 1);
            a += w1s[k] * Sb[(size_t)i1 * (NO * NO * NC) + e];
        }
        ob[e] = a;
    }
}

// ---------------------------------------------------------------------------
extern "C" void kernel_launch(void* const* d_in, const int* in_sizes, int n_in,
                              void* d_out, int out_size, void* d_ws, size_t ws_size,
                              hipStream_t stream) {
    (void)in_sizes; (void)n_in; (void)out_size;
    const float* img = (const float*)d_in[0];
    float* out = (float*)d_out;
    char* ws = (char*)d_ws;

    if (ws_size >= A1H_BYTES + A2H_BYTES) {
        __half* A1h = (__half*)ws;
        __half* A2h = (__half*)(ws + A1H_BYTES);
        k_p1<<<NB * NI * (NI / CH1), P1B, 0, stream>>>(img, A1h);
        int p2b = (int)((P2P_THREADS + 255) / 256);
        k_p2<<<p2b, 256, 0, stream>>>(A1h, A2h);
        int p3b = (int)((P3_THREADS + 255) / 256);
        k_p3<<<p3b, 256, 0, stream>>>(A2h, out);
    } else {
        float* S = (float*)ws;                       // 14.2 MB
        k_passA<<<NB * NI, 256, 0, stream>>>(img, S);
        k_passB<<<NB * NO, 256, 0, stream>>>(S, out);
    }
}